// Round 17
// baseline (341.032 us; speedup 1.0000x reference)
//
#include <hip/hip_runtime.h>
#include <hip/hip_bf16.h>

#define NN 10000
#define EE 100000
#define LL 9
#define HH 8
#define NLC (NN*LL*64)

typedef float f32x4 __attribute__((ext_vector_type(4)));
typedef short bf16x8 __attribute__((ext_vector_type(8)));
typedef unsigned short u16x4 __attribute__((ext_vector_type(4)));

__device__ __forceinline__ float sigmoidf_(float x){ return 1.0f/(1.0f+__expf(-x)); }
__device__ __forceinline__ unsigned short f2bf(float x){
  __hip_bfloat16 b = __float2bfloat16(x);
  return *reinterpret_cast<unsigned short*>(&b);
}
__device__ __forceinline__ float bf2f(unsigned short b){ return __uint_as_float(((unsigned)b)<<16); }

// A-fragment load from a [16][64] bf16 LDS plane with verified XOR swizzle (R5).
__device__ __forceinline__ bf16x8 ldA(const unsigned short* plane, int ln, int kt){
  const int row = ln & 15;
  const int col = (kt*32 + ((ln>>4)<<3)) ^ ((row & 7) << 3);
  return *(const bf16x8*)(plane + row*64 + col);
}

// Generic prep: W (64 x ncol) -> B-fragment-linear bf16 hi/lo, ncol/16 tiles.
__global__ __launch_bounds__(256) void k_prep_mat(
    const float* __restrict__ W, int ncol,
    unsigned short* __restrict__ bh, unsigned short* __restrict__ bl)
{
  const int t = blockIdx.x*256 + threadIdx.x;
  if (t >= (ncol>>4)*1024) return;
  const int i  = t & 7;
  const int ln = (t >> 3) & 63;
  const int kt = (t >> 9) & 1;
  const int nt = t >> 10;
  const int k  = kt*32 + ((ln>>4)<<3) + i;
  const int col = nt*16 + (ln & 15);
  const float v = W[k*ncol + col];
  const unsigned short h = f2bf(v);
  bh[t] = h;
  bl[t] = f2bf(v - bf2f(h));
}

// Prep: [Wv | Wa] (64 x 192) -> B-fragment-linear bf16 hi/lo (12 nt). Verified R5.
__global__ __launch_bounds__(256) void k_prep_vab(
    const float* __restrict__ Wv, const float* __restrict__ Wa,
    unsigned short* __restrict__ bh, unsigned short* __restrict__ bl)
{
  const int t = blockIdx.x*256 + threadIdx.x;
  if (t >= 12*1024) return;
  const int i  = t & 7;
  const int ln = (t >> 3) & 63;
  const int kt = (t >> 9) & 1;
  const int nt = t >> 10;
  const int k  = kt*32 + ((ln>>4)<<3) + i;
  const int col = nt*16 + (ln & 15);
  const float v = (col < 128) ? Wv[k*128 + col] : Wa[k*64 + (col - 128)];
  const unsigned short h = f2bf(v);
  bh[t] = h;
  bl[t] = f2bf(v - bf2f(h));
}

// K1: split-bf16 MFMA node linear: [16 x 64] @ [64 x 128(Ws|Wd)]. 256 thr, 16 rows/block.
__global__ __launch_bounds__(256) void k_node_lin_mfma(
    const float* __restrict__ x, const float* __restrict__ bs,
    const unsigned short* __restrict__ wsdh, const unsigned short* __restrict__ wsdl,
    float* __restrict__ xs, float* __restrict__ xd)
{
  const int tid = threadIdx.x, wid = tid>>6, ln = tid&63;
  const int base = blockIdx.x * 16;
  __shared__ unsigned short hx[2][16][64];
  {
    const int row = tid >> 4, c4 = (tid & 15) * 4;
    const float4 v = *(const float4*)&x[(size_t)(base+row)*64 + c4];
    const int cs = c4 ^ ((row & 7) << 3);
    u16x4 h, l;
    h[0]=f2bf(v.x); h[1]=f2bf(v.y); h[2]=f2bf(v.z); h[3]=f2bf(v.w);
    l[0]=f2bf(v.x-bf2f(h[0])); l[1]=f2bf(v.y-bf2f(h[1]));
    l[2]=f2bf(v.z-bf2f(h[2])); l[3]=f2bf(v.w-bf2f(h[3]));
    *(u16x4*)&hx[0][row][cs] = h;
    *(u16x4*)&hx[1][row][cs] = l;
  }
  __syncthreads();
  const bf16x8 ah0 = ldA(&hx[0][0][0], ln, 0);
  const bf16x8 ah1 = ldA(&hx[0][0][0], ln, 1);
  const bf16x8 al0 = ldA(&hx[1][0][0], ln, 0);
  const bf16x8 al1 = ldA(&hx[1][0][0], ln, 1);
  const bf16x8* Bh = (const bf16x8*)wsdh;
  const bf16x8* Bl = (const bf16x8*)wsdl;
  const int col = wid*16 + (ln & 15);
  const int r0  = (ln >> 4) * 4;
  #pragma unroll
  for (int g = 0; g < 2; g++){
    const int nt = g*4 + wid;
    f32x4 d = {0.f,0.f,0.f,0.f};
    const bf16x8 bh0 = Bh[(nt*2+0)*64 + ln];
    const bf16x8 bl0 = Bl[(nt*2+0)*64 + ln];
    const bf16x8 bh1 = Bh[(nt*2+1)*64 + ln];
    const bf16x8 bl1 = Bl[(nt*2+1)*64 + ln];
    d = __builtin_amdgcn_mfma_f32_16x16x32_bf16(ah0, bh0, d, 0, 0, 0);
    d = __builtin_amdgcn_mfma_f32_16x16x32_bf16(al0, bh0, d, 0, 0, 0);
    d = __builtin_amdgcn_mfma_f32_16x16x32_bf16(ah0, bl0, d, 0, 0, 0);
    d = __builtin_amdgcn_mfma_f32_16x16x32_bf16(ah1, bh1, d, 0, 0, 0);
    d = __builtin_amdgcn_mfma_f32_16x16x32_bf16(al1, bh1, d, 0, 0, 0);
    d = __builtin_amdgcn_mfma_f32_16x16x32_bf16(ah1, bl1, d, 0, 0, 0);
    float* out = (g == 0) ? xs : xd;
    #pragma unroll
    for (int i = 0; i < 4; i++){
      const int row = base + r0 + i;
      float o = d[i];
      if (g == 0 && row % LL == 0) o += bs[col];
      out[(size_t)row*64 + col] = o;
    }
  }
}

// ==================== SPLIT PATH ====================

// K2a: radial MLP + w2 GEMM -> wbuf bf16 (chunk-local rows). 512 thr, 16 edges/block, 8 KB LDS.
__global__ __launch_bounds__(512, 4) void k_radial_w2(
    const float* __restrict__ escal,
    const float* __restrict__ w1, const float* __restrict__ b1,
    const float* __restrict__ lnw, const float* __restrict__ lnb,
    const float* __restrict__ woff,
    const unsigned short* __restrict__ w2h, const unsigned short* __restrict__ w2l,
    int e0, unsigned short* __restrict__ wbuf)
{
  const int tid = threadIdx.x, wid = tid>>6, ln = tid&63;
  const int lbase = blockIdx.x * 16;
  const int base  = e0 + lbase;
  __shared__ float se[16][64];
  __shared__ unsigned short hpl[2][16][64];

  for (int i = tid; i < 1024; i += 512) se[i>>6][i&63] = escal[(size_t)base*64 + i];
  __syncthreads();

  {
    const int c = ln;
    const float bb = b1[c];
    float hv_[2] = {bb, bb};
    for (int kq = 0; kq < 16; kq++){
      const int k0 = kq*4;
      const float a0 = w1[(k0+0)*64+c], a1 = w1[(k0+1)*64+c], a2 = w1[(k0+2)*64+c], a3 = w1[(k0+3)*64+c];
      #pragma unroll
      for (int j = 0; j < 2; j++){
        const float4 xv = *(const float4*)&se[wid*2+j][k0];
        hv_[j] += xv.x*a0 + xv.y*a1 + xv.z*a2 + xv.w*a3;
      }
    }
    const float lw = lnw[c], lb = lnb[c];
    #pragma unroll
    for (int j = 0; j < 2; j++){
      const float v = hv_[j];
      float s1 = v, s2 = v*v;
      #pragma unroll
      for (int m = 1; m < 64; m <<= 1){ s1 += __shfl_xor(s1, m, 64); s2 += __shfl_xor(s2, m, 64); }
      const float mean = s1 * (1.0f/64.0f);
      const float var  = s2 * (1.0f/64.0f) - mean*mean;
      const float g = (v - mean) * rsqrtf(var + 1e-5f) * lw + lb;
      const float hj = g * sigmoidf_(g);
      const int er = wid*2 + j;
      const int cs = c ^ ((er & 7) << 3);
      const unsigned short hb = f2bf(hj);
      hpl[0][er][cs] = hb;
      hpl[1][er][cs] = f2bf(hj - bf2f(hb));
    }
  }
  __syncthreads();

  {
    const bf16x8 ah0 = ldA(&hpl[0][0][0], ln, 0);
    const bf16x8 ah1 = ldA(&hpl[0][0][0], ln, 1);
    const bf16x8 al0 = ldA(&hpl[1][0][0], ln, 0);
    const bf16x8 al1 = ldA(&hpl[1][0][0], ln, 1);
    const bf16x8* Bh = (const bf16x8*)w2h;
    const bf16x8* Bl = (const bf16x8*)w2l;
    const int q = ln >> 4, p = ln & 15;
    #pragma unroll
    for (int t5 = 0; t5 < 5; t5++){
      const int nt = wid + 8*t5;
      if (nt < 36){
        f32x4 d = {0.f,0.f,0.f,0.f};
        const bf16x8 bh0 = Bh[(nt*2+0)*64 + ln];
        const bf16x8 bl0 = Bl[(nt*2+0)*64 + ln];
        const bf16x8 bh1 = Bh[(nt*2+1)*64 + ln];
        const bf16x8 bl1 = Bl[(nt*2+1)*64 + ln];
        d = __builtin_amdgcn_mfma_f32_16x16x32_bf16(ah0, bh0, d, 0, 0, 0);
        d = __builtin_amdgcn_mfma_f32_16x16x32_bf16(al0, bh0, d, 0, 0, 0);
        d = __builtin_amdgcn_mfma_f32_16x16x32_bf16(ah0, bl0, d, 0, 0, 0);
        d = __builtin_amdgcn_mfma_f32_16x16x32_bf16(ah1, bh1, d, 0, 0, 0);
        d = __builtin_amdgcn_mfma_f32_16x16x32_bf16(al1, bh1, d, 0, 0, 0);
        d = __builtin_amdgcn_mfma_f32_16x16x32_bf16(ah1, bl1, d, 0, 0, 0);
        const int col = nt*16 + p;
        const float wo = woff[col];
        #pragma unroll
        for (int i = 0; i < 4; i++)
          wbuf[(size_t)(lbase + q*4 + i)*576 + col] = f2bf(d[i] + wo);
      }
    }
  }
}

// K2b: consume pass: gather + cp_tp1 -> value/gate/alpha MFMA -> epilogue + scatter.
// 512 thr, 16 edges/block, ~29 KB LDS -> 4 blocks/CU.
__global__ __launch_bounds__(512, 4) void k_edge_consume(
    const float* __restrict__ xsrc, const float* __restrict__ xdst,
    const float* __restrict__ eattr,
    const float* __restrict__ U1, const float* __restrict__ V1, const float* __restrict__ Y1,
    const float* __restrict__ U2, const float* __restrict__ V2, const float* __restrict__ Y2,
    const float* __restrict__ ba, const float* __restrict__ adot,
    const float* __restrict__ bv,
    const unsigned short* __restrict__ vabh, const unsigned short* __restrict__ vabl,
    const unsigned short* __restrict__ wbuf, int e0,
    const int* __restrict__ esrc, const int* __restrict__ edst,
    float* __restrict__ accum, float* __restrict__ asum)
{
  const int tid = threadIdx.x, wid = tid>>6, ln = tid&63;
  const int lbase = blockIdx.x * 16;
  const int base  = e0 + lbase;

  __shared__ unsigned short ms2[9][16][64];   // msg2 bf16 (swizzled), later value-D bf16 (swizzled)
  __shared__ float sga[2][16][64];            // gate / alpha D
  __shared__ float sU1[9][12], sV1[9][12], sU2[9][12], sV2[9][12];
  __shared__ float syv1[16][12], syv2[16][12];

  for (int i = tid; i < 81; i += 512){
    const int r9 = i/9, c9 = i%9;
    sU1[r9][c9]=U1[i]; sV1[r9][c9]=V1[i]; sU2[r9][c9]=U2[i]; sV2[r9][c9]=V2[i];
  }
  if (tid < 144){
    const int er = tid/9, r = tid%9;
    const float* ea = eattr + (size_t)(base+er)*9;
    float y1 = 0.f, y2 = 0.f;
    #pragma unroll
    for (int l = 0; l < 9; l++){ y1 += ea[l]*Y1[l*9+r]; y2 += ea[l]*Y2[l*9+r]; }
    syv1[er][r] = y1; syv2[er][r] = y2;
  }
  __syncthreads();

  // ---- gather + w read + cp_tp1 -> ms2 bf16 ----
  {
    const int c = ln;
    const int er0 = wid*2;
    float msg[2][9];
    #pragma unroll
    for (int j = 0; j < 2; j++){
      const int e  = base + er0 + j;
      const int src = esrc[e], dst = edst[e];
      const float* ps = xsrc + (size_t)src*576 + c;
      const float* pd = xdst + (size_t)dst*576 + c;
      #pragma unroll
      for (int l = 0; l < 9; l++) msg[j][l] = ps[l*64] + pd[l*64];
    }
    float xv[2][9];
    #pragma unroll
    for (int j = 0; j < 2; j++)
      #pragma unroll
      for (int r = 0; r < 9; r++) xv[j][r] = 0.f;
    #pragma unroll
    for (int l = 0; l < 9; l++){
      const float4 v0 = *(const float4*)&sV1[l][0];
      const float4 v1 = *(const float4*)&sV1[l][4];
      const float  v2 = sV1[l][8];
      #pragma unroll
      for (int j = 0; j < 2; j++){
        const float m = msg[j][l];
        xv[j][0] += m*v0.x; xv[j][1] += m*v0.y; xv[j][2] += m*v0.z; xv[j][3] += m*v0.w;
        xv[j][4] += m*v1.x; xv[j][5] += m*v1.y; xv[j][6] += m*v1.z; xv[j][7] += m*v1.w;
        xv[j][8] += m*v2;
      }
    }
    #pragma unroll
    for (int j = 0; j < 2; j++){
      const int er = er0 + j;
      const unsigned short* wb = wbuf + (size_t)(lbase + er)*576 + c;
      const float4 s0 = *(const float4*)&syv1[er][0];
      const float4 s1 = *(const float4*)&syv1[er][4];
      const float  s2 = syv1[er][8];
      const float sy[9] = {s0.x,s0.y,s0.z,s0.w,s1.x,s1.y,s1.z,s1.w,s2};
      #pragma unroll
      for (int r = 0; r < 9; r++) xv[j][r] *= sy[r] * bf2f(wb[r*64]);
    }
    #pragma unroll
    for (int l = 0; l < 9; l++){
      const float4 u0 = *(const float4*)&sU1[l][0];
      const float4 u1 = *(const float4*)&sU1[l][4];
      const float  u2 = sU1[l][8];
      #pragma unroll
      for (int j = 0; j < 2; j++){
        const int er = er0 + j;
        const float m2 = xv[j][0]*u0.x + xv[j][1]*u0.y + xv[j][2]*u0.z + xv[j][3]*u0.w
                       + xv[j][4]*u1.x + xv[j][5]*u1.y + xv[j][6]*u1.z + xv[j][7]*u1.w
                       + xv[j][8]*u2;
        ms2[l][er][c ^ ((er & 7) << 3)] = f2bf(m2);
      }
    }
  }
  __syncthreads();

  // ---- value GEMM (waves 0..3, regs) / gate+alpha (waves 4..7 -> sga) ----
  f32x4 vacc[9];
  {
    const bf16x8* Bh = (const bf16x8*)vabh;
    const bf16x8* Bl = (const bf16x8*)vabl;
    if (wid < 4){
      const int nt = wid;
      const bf16x8 bh0 = Bh[(nt*2+0)*64 + ln];
      const bf16x8 bl0 = Bl[(nt*2+0)*64 + ln];
      const bf16x8 bh1 = Bh[(nt*2+1)*64 + ln];
      const bf16x8 bl1 = Bl[(nt*2+1)*64 + ln];
      #pragma unroll
      for (int l = 0; l < 9; l++){
        const bf16x8 a0 = ldA(&ms2[l][0][0], ln, 0);
        const bf16x8 a1 = ldA(&ms2[l][0][0], ln, 1);
        f32x4 d = {0.f,0.f,0.f,0.f};
        d = __builtin_amdgcn_mfma_f32_16x16x32_bf16(a0, bh0, d, 0, 0, 0);
        d = __builtin_amdgcn_mfma_f32_16x16x32_bf16(a0, bl0, d, 0, 0, 0);
        d = __builtin_amdgcn_mfma_f32_16x16x32_bf16(a1, bh1, d, 0, 0, 0);
        d = __builtin_amdgcn_mfma_f32_16x16x32_bf16(a1, bl1, d, 0, 0, 0);
        vacc[l] = d;
      }
    } else {
      const int w4 = wid - 4;
      const bf16x8 a0 = ldA(&ms2[0][0][0], ln, 0);
      const bf16x8 a1 = ldA(&ms2[0][0][0], ln, 1);
      const int q = ln >> 4, p = ln & 15;
      #pragma unroll
      for (int gg = 0; gg < 2; gg++){
        const int nt = 4 + gg*4 + w4;
        const bf16x8 bh0 = Bh[(nt*2+0)*64 + ln];
        const bf16x8 bl0 = Bl[(nt*2+0)*64 + ln];
        const bf16x8 bh1 = Bh[(nt*2+1)*64 + ln];
        const bf16x8 bl1 = Bl[(nt*2+1)*64 + ln];
        f32x4 d = {0.f,0.f,0.f,0.f};
        d = __builtin_amdgcn_mfma_f32_16x16x32_bf16(a0, bh0, d, 0, 0, 0);
        d = __builtin_amdgcn_mfma_f32_16x16x32_bf16(a0, bl0, d, 0, 0, 0);
        d = __builtin_amdgcn_mfma_f32_16x16x32_bf16(a1, bh1, d, 0, 0, 0);
        d = __builtin_amdgcn_mfma_f32_16x16x32_bf16(a1, bl1, d, 0, 0, 0);
        #pragma unroll
        for (int i = 0; i < 4; i++) sga[gg][q*4+i][w4*16+p] = d[i];
      }
    }
  }
  __syncthreads();

  if (wid < 4){
    const int col = wid*16 + (ln & 15);
    const int r0  = (ln >> 4) * 4;
    #pragma unroll
    for (int l = 0; l < 9; l++)
      #pragma unroll
      for (int i = 0; i < 4; i++){
        const int er = r0 + i;
        ms2[l][er][col ^ ((er & 7) << 3)] = f2bf(vacc[l][i]);
      }
  }
  __syncthreads();

  // ---- epilogue: ALL 8 waves, 2 edges/wave ----
  {
    const int c = ln;
    const int er0 = wid*2;
    const float bvc = bv[c], bgc = bv[64+c], bac = ba[c], adc = adot[c];
    int dsti[2]; float gsv[2], pev[2];
    #pragma unroll
    for (int j = 0; j < 2; j++){
      const int er = er0 + j;
      dsti[j] = edst[base + er];
      gsv[j] = sigmoidf_(sga[0][er][c] + bgc);
      const float a  = sga[1][er][c] + bac;
      const float sl = 0.2f*a + 0.8f*a*sigmoidf_(a);
      float t = sl * adc;
      t += __shfl_xor(t, 1, 64);
      t += __shfl_xor(t, 2, 64);
      t += __shfl_xor(t, 4, 64);
      pev[j] = __expf(t);     // unnormalized softmax weight (max-shift cancels)
      if ((c & 7) == 0) atomicAdd(&asum[(size_t)dsti[j]*8 + (c>>3)], pev[j]);
    }
    float tmp2[2][9];
    #pragma unroll
    for (int j = 0; j < 2; j++)
      #pragma unroll
      for (int r = 0; r < 9; r++) tmp2[j][r] = 0.f;
    #pragma unroll
    for (int l = 0; l < 9; l++){
      const float4 v0 = *(const float4*)&sV2[l][0];
      const float4 v1 = *(const float4*)&sV2[l][4];
      const float  v2 = sV2[l][8];
      #pragma unroll
      for (int j = 0; j < 2; j++){
        const int er = er0 + j;
        float v = bf2f(ms2[l][er][c ^ ((er & 7) << 3)]);
        if (l == 0){ v += bvc; v = v * sigmoidf_(v); }
        else v *= gsv[j];
        tmp2[j][0] += v*v0.x; tmp2[j][1] += v*v0.y; tmp2[j][2] += v*v0.z; tmp2[j][3] += v*v0.w;
        tmp2[j][4] += v*v1.x; tmp2[j][5] += v*v1.y; tmp2[j][6] += v*v1.z; tmp2[j][7] += v*v1.w;
        tmp2[j][8] += v*v2;
      }
    }
    #pragma unroll
    for (int j = 0; j < 2; j++){
      const int er = er0 + j;
      const unsigned short* wb = wbuf + (size_t)(lbase + er)*576 + c;
      const float4 s0 = *(const float4*)&syv2[er][0];
      const float4 s1 = *(const float4*)&syv2[er][4];
      const float  s2 = syv2[er][8];
      const float sy[9] = {s0.x,s0.y,s0.z,s0.w,s1.x,s1.y,s1.z,s1.w,s2};
      #pragma unroll
      for (int r = 0; r < 9; r++) tmp2[j][r] *= sy[r] * bf2f(wb[r*64]) * pev[j];
    }
    #pragma unroll
    for (int l = 0; l < 9; l++){
      const float4 u0 = *(const float4*)&sU2[l][0];
      const float4 u1 = *(const float4*)&sU2[l][4];
      const float  u2 = sU2[l][8];
      #pragma unroll
      for (int j = 0; j < 2; j++){
        const float o = tmp2[j][0]*u0.x + tmp2[j][1]*u0.y + tmp2[j][2]*u0.z + tmp2[j][3]*u0.w
                      + tmp2[j][4]*u1.x + tmp2[j][5]*u1.y + tmp2[j][6]*u1.z + tmp2[j][7]*u1.w
                      + tmp2[j][8]*u2;
        atomicAdd(accum + (size_t)dsti[j]*576 + l*64 + c, o);
      }
    }
  }
}

// ==================== FUSED FALLBACK (R16) ====================
__global__ __launch_bounds__(512, 4) void k_edge_fused(
    const float* __restrict__ xsrc, const float* __restrict__ xdst,
    const float* __restrict__ eattr, const float* __restrict__ escal,
    const float* __restrict__ w1, const float* __restrict__ b1,
    const float* __restrict__ lnw, const float* __restrict__ lnb,
    const float* __restrict__ woff,
    const float* __restrict__ U1, const float* __restrict__ V1, const float* __restrict__ Y1,
    const float* __restrict__ U2, const float* __restrict__ V2, const float* __restrict__ Y2,
    const float* __restrict__ ba, const float* __restrict__ adot,
    const float* __restrict__ bv,
    const unsigned short* __restrict__ w2h, const unsigned short* __restrict__ w2l,
    const unsigned short* __restrict__ vabh, const unsigned short* __restrict__ vabl,
    const int* __restrict__ esrc, const int* __restrict__ edst,
    float* __restrict__ accum, float* __restrict__ asum)
{
  const int tid = threadIdx.x;
  const int wid = tid >> 6;
  const int ln  = tid & 63;
  const int base = blockIdx.x * 16;

  __shared__ float sgse[2][16][64];
  __shared__ unsigned short wle[16][576];
  __shared__ unsigned short ms2[9][16][64];
  __shared__ float sU1[9][12], sV1[9][12], sU2[9][12], sV2[9][12];
  __shared__ float syv1[16][12], syv2[16][12];
  float (*se)[64] = sgse[0];
  unsigned short* hpl = (unsigned short*)&sgse[1][0][0];

  for (int i = tid; i < 81; i += 512){
    const int r9 = i/9, c9 = i%9;
    sU1[r9][c9]=U1[i]; sV1[r9][c9]=V1[i]; sU2[r9][c9]=U2[i]; sV2[r9][c9]=V2[i];
  }
  if (tid < 144){
    const int er = tid/9, r = tid%9;
    const float* ea = eattr + (size_t)(base+er)*9;
    float y1 = 0.f, y2 = 0.f;
    #pragma unroll
    for (int l = 0; l < 9; l++){ y1 += ea[l]*Y1[l*9+r]; y2 += ea[l]*Y2[l*9+r]; }
    syv1[er][r] = y1; syv2[er][r] = y2;
  }
  for (int i = tid; i < 1024; i += 512) se[i>>6][i&63] = escal[(size_t)base*64 + i];
  __syncthreads();

  {
    const int c = ln;
    const float bb = b1[c];
    float hv_[2] = {bb, bb};
    for (int kq = 0; kq < 16; kq++){
      const int k0 = kq*4;
      const float a0 = w1[(k0+0)*64+c], a1 = w1[(k0+1)*64+c], a2 = w1[(k0+2)*64+c], a3 = w1[(k0+3)*64+c];
      #pragma unroll
      for (int j = 0; j < 2; j++){
        const float4 xv = *(const float4*)&se[wid*2+j][k0];
        hv_[j] += xv.x*a0 + xv.y*a1 + xv.z*a2 + xv.w*a3;
      }
    }
    const float lw = lnw[c], lb = lnb[c];
    #pragma unroll
    for (int j = 0; j < 2; j++){
      const float v = hv_[j];
      float s1 = v, s2 = v*v;
      #pragma unroll
      for (int m = 1; m < 64; m <<= 1){ s1 += __shfl_xor(s1, m, 64); s2 += __shfl_xor(s2, m, 64); }
      const float mean = s1 * (1.0f/64.0f);
      const float var  = s2 * (1.0f/64.0f) - mean*mean;
      const float g = (v - mean) * rsqrtf(var + 1e-5f) * lw + lb;
      const float hj = g * sigmoidf_(g);
      const int er = wid*2 + j;
      const int cs = c ^ ((er & 7) << 3);
      const unsigned short hb = f2bf(hj);
      hpl[(0*16 + er)*64 + cs] = hb;
      hpl[(1*16 + er)*64 + cs] = f2bf(hj - bf2f(hb));
    }
  }
  __syncthreads();

  {
    const bf16x8 ah0 = ldA(hpl, ln, 0);
    const bf16x8 ah1 = ldA(hpl, ln, 1);
    const bf16x8 al0 = ldA(hpl + 16*64, ln, 0);
    const bf16x8 al1 = ldA(hpl + 16*64, ln, 1);
    const bf16x8* Bh = (const bf16x8*)w2h;
    const bf16x8* Bl = (const bf16x8*)w2l;
    const int q = ln >> 4, p = ln & 15;
    #pragma unroll
    for (int t5 = 0; t5 < 5; t5++){
      const int nt = wid + 8*t5;
      if (nt < 36){
        f32x4 d = {0.f,0.f,0.f,0.f};
        const bf16x8 bh0 = Bh[(nt*2+0)*64 + ln];
        const bf16x8 bl0 = Bl[(nt*2+0)*64 + ln];
        const bf16x8 bh1 = Bh[(nt*2+1)*64 + ln];
        const bf16x8 bl1 = Bl[(nt*2+1)*64 + ln];
        d = __builtin_amdgcn_mfma_f32_16x16x32_bf16(ah0, bh0, d, 0, 0, 0);
        d = __builtin_amdgcn_mfma_f32_16x16x32_bf16(al0, bh0, d, 0, 0, 0);
        d = __builtin_amdgcn_mfma_f32_16x16x32_bf16(ah0, bl0, d, 0, 0, 0);
        d = __builtin_amdgcn_mfma_f32_16x16x32_bf16(ah1, bh1, d, 0, 0, 0);
        d = __builtin_amdgcn_mfma_f32_16x16x32_bf16(al1, bh1, d, 0, 0, 0);
        d = __builtin_amdgcn_mfma_f32_16x16x32_bf16(ah1, bl1, d, 0, 0, 0);
        const int col = nt*16 + p;
        const float wo = woff[col];
        #pragma unroll
        for (int i = 0; i < 4; i++) wle[q*4+i][col] = f2bf(d[i] + wo);
      }
    }
  }
  __syncthreads();

  {
    const int c = ln;
    const int er0 = wid*2;
    float msg[2][9];
    #pragma unroll
    for (int j = 0; j < 2; j++){
      const int e  = base + er0 + j;
      const int src = esrc[e], dst = edst[e];
      const float* ps = xsrc + (size_t)src*576 + c;
      const float* pd = xdst + (size_t)dst*576 + c;
      #pragma unroll
      for (int l = 0; l < 9; l++) msg[j][l] = ps[l*64] + pd[l*64];
    }
    float xv[2][9];
    #pragma unroll
    for (int j = 0; j < 2; j++)
      #pragma unroll
      for (int r = 0; r < 9; r++) xv[j][r] = 0.f;
    #pragma unroll
    for (int l = 0; l < 9; l++){
      const float4 v0 = *(const float4*)&sV1[l][0];
      const float4 v1 = *(const float4*)&sV1[l][4];
      const float  v2 = sV1[l][8];
      #pragma unroll
      for (int j = 0; j < 2; j++){
        const float m = msg[j][l];
        xv[j][0] += m*v0.x; xv[j][1] += m*v0.y; xv[j][2] += m*v0.z; xv[j][3] += m*v0.w;
        xv[j][4] += m*v1.x; xv[j][5] += m*v1.y; xv[j][6] += m*v1.z; xv[j][7] += m*v1.w;
        xv[j][8] += m*v2;
      }
    }
    #pragma unroll
    for (int j = 0; j < 2; j++){
      const int er = er0 + j;
      const float4 s0 = *(const float4*)&syv1[er][0];
      const float4 s1 = *(const float4*)&syv1[er][4];
      const float  s2 = syv1[er][8];
      const float sy[9] = {s0.x,s0.y,s0.z,s0.w,s1.x,s1.y,s1.z,s1.w,s2};
      #pragma unroll
      for (int r = 0; r < 9; r++) xv[j][r] *= sy[r] * bf2f(wle[er][r*64+c]);
    }
    #pragma unroll
    for (int l = 0; l < 9; l++){
      const float4 u0 = *(const float4*)&sU1[l][0];
      const float4 u1 = *(const float4*)&sU1[l][4];
      const float  u2 = sU1[l][8];
      #pragma unroll
      for (int j = 0; j < 2; j++){
        const int er = er0 + j;
        const float m2 = xv[j][0]*u0.x + xv[j][1]*u0.y + xv[j][2]*u0.z + xv[j][3]*u0.w
                       + xv[j][4]*u1.x + xv[j][5]*u1.y + xv[j][6]*u1.z + xv[j][7]*u1.w
                       + xv[j][8]*u2;
        ms2[l][er][c ^ ((er & 7) << 3)] = f2bf(m2);
      }
    }
  }
  __syncthreads();

  f32x4 vacc[9];
  {
    const bf16x8* Bh = (const bf16x8*)vabh;
    const bf16x8* Bl = (const bf16x8*)vabl;
    if (wid < 4){
      const int nt = wid;
      const bf16x8 bh0 = Bh[(nt*2+0)*64 + ln];
      const bf16x8 bl0 = Bl[(nt*2+0)*64 + ln];
      const bf16x8 bh1 = Bh[(nt*2+1)*64 + ln];
      const bf16x8 bl1 = Bl[(nt*2+1)*64 + ln];
      #pragma unroll
      for (int l = 0; l < 9; l++){
        const bf16x8 a0 = ldA(&ms2[l][0][0], ln, 0);
        const bf16x8 a1 = ldA(&ms2[l][0][0], ln, 1);
        f32x4 d = {0.f,0.f,0.f,0.f};
        d = __builtin_amdgcn_mfma_f32_16x16x32_bf16(a0, bh0, d, 0, 0, 0);
        d = __builtin_amdgcn_mfma_f32_16x16x32_bf16(a0, bl0, d, 0, 0, 0);
        d = __builtin_amdgcn_mfma_f32_16x16x32_bf16(a1, bh1, d, 0, 0, 0);
        d = __builtin_amdgcn_mfma_f32_16x16x32_bf16(a1, bl1, d, 0, 0, 0);
        vacc[l] = d;
      }
    } else {
      const int w4 = wid - 4;
      const bf16x8 a0 = ldA(&ms2[0][0][0], ln, 0);
      const bf16x8 a1 = ldA(&ms2[0][0][0], ln, 1);
      const int q = ln >> 4, p = ln & 15;
      #pragma unroll
      for (int gg = 0; gg < 2; gg++){
        const int nt = 4 + gg*4 + w4;
        const bf16x8 bh0 = Bh[(nt*2+0)*64 + ln];
        const bf16x8 bl0 = Bl[(nt*2+0)*64 + ln];
        const bf16x8 bh1 = Bh[(nt*2+1)*64 + ln];
        const bf16x8 bl1 = Bl[(nt*2+1)*64 + ln];
        f32x4 d = {0.f,0.f,0.f,0.f};
        d = __builtin_amdgcn_mfma_f32_16x16x32_bf16(a0, bh0, d, 0, 0, 0);
        d = __builtin_amdgcn_mfma_f32_16x16x32_bf16(a0, bl0, d, 0, 0, 0);
        d = __builtin_amdgcn_mfma_f32_16x16x32_bf16(a1, bh1, d, 0, 0, 0);
        d = __builtin_amdgcn_mfma_f32_16x16x32_bf16(a1, bl1, d, 0, 0, 0);
        #pragma unroll
        for (int i = 0; i < 4; i++) sgse[gg][q*4+i][w4*16+p] = d[i];
      }
    }
  }
  __syncthreads();

  if (wid < 4){
    const int col = wid*16 + (ln & 15);
    const int r0  = (ln >> 4) * 4;
    #pragma unroll
    for (int l = 0; l < 9; l++)
      #pragma unroll
      for (int i = 0; i < 4; i++){
        const int er = r0 + i;
        ms2[l][er][col ^ ((er & 7) << 3)] = f2bf(vacc[l][i]);
      }
  }
  __syncthreads();

  {
    const int c = ln;
    const int er0 = wid*2;
    const float bvc = bv[c], bgc = bv[64+c], bac = ba[c], adc = adot[c];
    int dsti[2]; float gsv[2], pev[2];
    #pragma unroll
    for (int j = 0; j < 2; j++){
      const int er = er0 + j;
      dsti[j] = edst[base + er];
      gsv[j] = sigmoidf_(sgse[0][er][c] + bgc);
      const float a  = sgse[1][er][c] + bac;
      const float sl = 0.2f*a + 0.8f*a*sigmoidf_(a);
      float t = sl * adc;
      t += __shfl_xor(t, 1, 64);
      t += __shfl_xor(t, 2, 64);
      t += __shfl_xor(t, 4, 64);
      pev[j] = __expf(t);
      if ((c & 7) == 0) atomicAdd(&asum[(size_t)dsti[j]*8 + (c>>3)], pev[j]);
    }
    float tmp2[2][9];
    #pragma unroll
    for (int j = 0; j < 2; j++)
      #pragma unroll
      for (int r = 0; r < 9; r++) tmp2[j][r] = 0.f;
    #pragma unroll
    for (int l = 0; l < 9; l++){
      const float4 v0 = *(const float4*)&sV2[l][0];
      const float4 v1 = *(const float4*)&sV2[l][4];
      const float  v2 = sV2[l][8];
      #pragma unroll
      for (int j = 0; j < 2; j++){
        const int er = er0 + j;
        float v = bf2f(ms2[l][er][c ^ ((er & 7) << 3)]);
        if (l == 0){ v += bvc; v = v * sigmoidf_(v); }
        else v *= gsv[j];
        tmp2[j][0] += v*v0.x; tmp2[j][1] += v*v0.y; tmp2[j][2] += v*v0.z; tmp2[j][3] += v*v0.w;
        tmp2[j][4] += v*v1.x; tmp2[j][5] += v*v1.y; tmp2[j][6] += v*v1.z; tmp2[j][7] += v*v1.w;
        tmp2[j][8] += v*v2;
      }
    }
    #pragma unroll
    for (int j = 0; j < 2; j++){
      const int er = er0 + j;
      const float4 s0 = *(const float4*)&syv2[er][0];
      const float4 s1 = *(const float4*)&syv2[er][4];
      const float  s2 = syv2[er][8];
      const float sy[9] = {s0.x,s0.y,s0.z,s0.w,s1.x,s1.y,s1.z,s1.w,s2};
      #pragma unroll
      for (int r = 0; r < 9; r++) tmp2[j][r] *= sy[r] * bf2f(wle[er][r*64+c]) * pev[j];
    }
    #pragma unroll
    for (int l = 0; l < 9; l++){
      const float4 u0 = *(const float4*)&sU2[l][0];
      const float4 u1 = *(const float4*)&sU2[l][4];
      const float  u2 = sU2[l][8];
      #pragma unroll
      for (int j = 0; j < 2; j++){
        const float o = tmp2[j][0]*u0.x + tmp2[j][1]*u0.y + tmp2[j][2]*u0.z + tmp2[j][3]*u0.w
                      + tmp2[j][4]*u1.x + tmp2[j][5]*u1.y + tmp2[j][6]*u1.z + tmp2[j][7]*u1.w
                      + tmp2[j][8]*u2;
        atomicAdd(accum + (size_t)dsti[j]*576 + l*64 + c, o);
      }
    }
  }
}

// K3: normalize + proj via split-bf16 MFMA. 256 thr, 16 rows/block.
__global__ __launch_bounds__(256) void k_norm_proj_mfma(
    const float* __restrict__ acc, const float* __restrict__ asum,
    const unsigned short* __restrict__ wph, const unsigned short* __restrict__ wpl,
    const float* __restrict__ bp, float* __restrict__ out)
{
  const int tid = threadIdx.x, wid = tid>>6, ln = tid&63;
  const int base = blockIdx.x * 16;
  __shared__ unsigned short hx[2][16][64];
  {
    const int row = tid >> 4, c4 = (tid & 15) * 4;
    const int grow = base + row;
    const float s = 1.0f / (asum[(size_t)(grow/9)*8 + (c4>>3)] + 1e-16f);
    float4 v = *(const float4*)&acc[(size_t)grow*64 + c4];
    v.x *= s; v.y *= s; v.z *= s; v.w *= s;
    const int cs = c4 ^ ((row & 7) << 3);
    u16x4 h, l;
    h[0]=f2bf(v.x); h[1]=f2bf(v.y); h[2]=f2bf(v.z); h[3]=f2bf(v.w);
    l[0]=f2bf(v.x-bf2f(h[0])); l[1]=f2bf(v.y-bf2f(h[1]));
    l[2]=f2bf(v.z-bf2f(h[2])); l[3]=f2bf(v.w-bf2f(h[3]));
    *(u16x4*)&hx[0][row][cs] = h;
    *(u16x4*)&hx[1][row][cs] = l;
  }
  __syncthreads();
  const bf16x8 ah0 = ldA(&hx[0][0][0], ln, 0);
  const bf16x8 ah1 = ldA(&hx[0][0][0], ln, 1);
  const bf16x8 al0 = ldA(&hx[1][0][0], ln, 0);
  const bf16x8 al1 = ldA(&hx[1][0][0], ln, 1);
  const bf16x8* Bh = (const bf16x8*)wph;
  const bf16x8* Bl = (const bf16x8*)wpl;
  const int nt = wid;
  f32x4 d = {0.f,0.f,0.f,0.f};
  const bf16x8 bh0 = Bh[(nt*2+0)*64 + ln];
  const bf16x8 bl0 = Bl[(nt*2+0)*64 + ln];
  const bf16x8 bh1 = Bh[(nt*2+1)*64 + ln];
  const bf16x8 bl1 = Bl[(nt*2+1)*64 + ln];
  d = __builtin_amdgcn_mfma_f32_16x16x32_bf16(ah0, bh0, d, 0, 0, 0);
  d = __builtin_amdgcn_mfma_f32_16x16x32_bf16(al0, bh0, d, 0, 0, 0);
  d = __builtin_amdgcn_mfma_f32_16x16x32_bf16(ah0, bl0, d, 0, 0, 0);
  d = __builtin_amdgcn_mfma_f32_16x16x32_bf16(ah1, bh1, d, 0, 0, 0);
  d = __builtin_amdgcn_mfma_f32_16x16x32_bf16(al1, bh1, d, 0, 0, 0);
  d = __builtin_amdgcn_mfma_f32_16x16x32_bf16(ah1, bl1, d, 0, 0, 0);
  const int col = wid*16 + (ln & 15);
  const int r0  = (ln >> 4) * 4;
  #pragma unroll
  for (int i = 0; i < 4; i++){
    const int row = base + r0 + i;
    float o = d[i];
    if (row % LL == 0) o += bp[col];
    out[(size_t)row*64 + col] = o;
  }
}

extern "C" void kernel_launch(void* const* d_in, const int* in_sizes, int n_in,
                              void* d_out, int out_size, void* d_ws, size_t ws_size,
                              hipStream_t stream)
{
  (void)in_sizes; (void)n_in; (void)out_size;
  const float* node_input = (const float*)d_in[0];
  const float* edge_attr  = (const float*)d_in[1];
  const float* edge_scal  = (const float*)d_in[2];
  const float* W_src   = (const float*)d_in[3];
  const float* b_src   = (const float*)d_in[4];
  const float* W_dst   = (const float*)d_in[5];
  const float* rad_w1  = (const float*)d_in[6];
  const float* rad_b1  = (const float*)d_in[7];
  const float* rad_ln_w= (const float*)d_in[8];
  const float* rad_ln_b= (const float*)d_in[9];
  const float* rad_w2  = (const float*)d_in[10];
  const float* rad_off = (const float*)d_in[11];
  const float* U1 = (const float*)d_in[12];
  const float* V1 = (const float*)d_in[13];
  const float* Y1 = (const float*)d_in[14];
  const float* U2 = (const float*)d_in[15];
  const float* V2 = (const float*)d_in[16];
  const float* Y2 = (const float*)d_in[17];
  const float* W_alpha = (const float*)d_in[18];
  const float* b_alpha = (const float*)d_in[19];
  const float* alpha_dot = (const float*)d_in[20];
  const float* W_value = (const float*)d_in[21];
  const float* b_value = (const float*)d_in[22];
  const float* W_proj  = (const float*)d_in[23];
  const float* b_proj  = (const float*)d_in[24];
  const int* esrc = (const int*)d_in[25];
  const int* edst = (const int*)d_in[26];

  float* xsrc  = (float*)d_ws;
  float* xdst  = xsrc + NLC;
  float* accum = xdst + NLC;
  float* asum  = accum + NLC;
  unsigned short* w2h  = (unsigned short*)(asum + (size_t)NN*HH);
  unsigned short* w2l  = w2h + 36*1024;
  unsigned short* vabh = w2l + 36*1024;
  unsigned short* vabl = vabh + 12*1024;
  unsigned short* wsdh = vabl + 12*1024;
  unsigned short* wsdl = wsdh + 8*1024;
  unsigned short* wph  = wsdl + 8*1024;
  unsigned short* wpl  = wph  + 4*1024;
  unsigned short* wbuf = wpl  + 4*1024;
  const size_t base_need = ((size_t)3*NLC + (size_t)NN*HH)*sizeof(float)
                         + (size_t)(2*36*1024 + 2*12*1024 + 2*8*1024 + 2*4*1024)*sizeof(unsigned short);
  if (ws_size < base_need) return;

  // choose chunk size for the split path (wbuf = CS*576 bf16)
  int CS = 0;
  const int cands[4] = {100000, 50000, 20000, 10000};
  for (int i = 0; i < 4; i++){
    if (base_need + (size_t)cands[i]*576*sizeof(unsigned short) <= ws_size){ CS = cands[i]; break; }
  }

  hipMemsetAsync(accum, 0, (size_t)NLC*sizeof(float), stream);
  hipMemsetAsync(asum, 0, (size_t)NN*HH*sizeof(float), stream);

  k_prep_mat<<<144, 256, 0, stream>>>(rad_w2, 576, w2h, w2l);
  k_prep_vab<<<48, 256, 0, stream>>>(W_value, W_alpha, vabh, vabl);
  k_prep_mat<<<16, 256, 0, stream>>>(W_src, 64, wsdh, wsdl);
  k_prep_mat<<<16, 256, 0, stream>>>(W_dst, 64, wsdh + 4*1024, wsdl + 4*1024);
  k_prep_mat<<<16, 256, 0, stream>>>(W_proj, 64, wph, wpl);
  k_node_lin_mfma<<<NN*LL/16, 256, 0, stream>>>(node_input, b_src, wsdh, wsdl, xsrc, xdst);

  if (CS > 0){
    for (int e0 = 0; e0 < EE; e0 += CS){
      const int n = (EE - e0 < CS) ? (EE - e0) : CS;
      k_radial_w2<<<n/16, 512, 0, stream>>>(edge_scal, rad_w1, rad_b1, rad_ln_w, rad_ln_b,
          rad_off, w2h, w2l, e0, wbuf);
      k_edge_consume<<<n/16, 512, 0, stream>>>(xsrc, xdst, edge_attr,
          U1, V1, Y1, U2, V2, Y2, b_alpha, alpha_dot, b_value,
          vabh, vabl, wbuf, e0, esrc, edst, accum, asum);
    }
  } else {
    k_edge_fused<<<EE/16, 512, 0, stream>>>(xsrc, xdst, edge_attr, edge_scal,
        rad_w1, rad_b1, rad_ln_w, rad_ln_b, rad_off,
        U1, V1, Y1, U2, V2, Y2,
        b_alpha, alpha_dot, b_value,
        w2h, w2l, vabh, vabl, esrc, edst, accum, asum);
  }

  k_norm_proj_mfma<<<NN*LL/16, 256, 0, stream>>>(accum, asum, wph, wpl, b_proj, (float*)d_out);
}

// Round 18
// 283.270 us; speedup vs baseline: 1.2039x; 1.2039x over previous
//
#include <hip/hip_runtime.h>
#include <hip/hip_bf16.h>

#define NN 10000
#define EE 100000
#define LL 9
#define HH 8
#define NLC (NN*LL*64)

typedef float f32x4 __attribute__((ext_vector_type(4)));
typedef short bf16x8 __attribute__((ext_vector_type(8)));
typedef unsigned short u16x4 __attribute__((ext_vector_type(4)));

__device__ __forceinline__ float sigmoidf_(float x){ return 1.0f/(1.0f+__expf(-x)); }
__device__ __forceinline__ unsigned short f2bf(float x){
  __hip_bfloat16 b = __float2bfloat16(x);
  return *reinterpret_cast<unsigned short*>(&b);
}
__device__ __forceinline__ float bf2f(unsigned short b){ return __uint_as_float(((unsigned)b)<<16); }

// A-fragment load from a [16][64] bf16 LDS plane with verified XOR swizzle (R5).
__device__ __forceinline__ bf16x8 ldA(const unsigned short* plane, int ln, int kt){
  const int row = ln & 15;
  const int col = (kt*32 + ((ln>>4)<<3)) ^ ((row & 7) << 3);
  return *(const bf16x8*)(plane + row*64 + col);
}

// Combined prep: all 5 weight matrices -> B-fragment-linear bf16 hi/lo in one launch.
// t-ranges: [0,36864) rad_w2 | [36864,49152) Wv|Wa | [49152,53248) W_src |
//           [53248,57344) W_dst | [57344,61440) W_proj
__global__ __launch_bounds__(256) void k_prep_all(
    const float* __restrict__ w2, const float* __restrict__ Wv, const float* __restrict__ Wa,
    const float* __restrict__ Ws, const float* __restrict__ Wd, const float* __restrict__ Wp,
    unsigned short* __restrict__ w2h, unsigned short* __restrict__ w2l,
    unsigned short* __restrict__ vabh, unsigned short* __restrict__ vabl,
    unsigned short* __restrict__ wsdh, unsigned short* __restrict__ wsdl,
    unsigned short* __restrict__ wph, unsigned short* __restrict__ wpl)
{
  const int t = blockIdx.x*256 + threadIdx.x;
  if (t >= 61440) return;
  int u, which;
  if      (t < 36864){ u = t;         which = 0; }
  else if (t < 49152){ u = t - 36864; which = 1; }
  else if (t < 53248){ u = t - 49152; which = 2; }
  else if (t < 57344){ u = t - 53248; which = 3; }
  else               { u = t - 57344; which = 4; }
  const int i  = u & 7;
  const int ln = (u >> 3) & 63;
  const int kt = (u >> 9) & 1;
  const int nt = u >> 10;
  const int k  = kt*32 + ((ln>>4)<<3) + i;
  const int col = nt*16 + (ln & 15);
  float v;
  unsigned short *dh, *dl;
  int di;
  switch (which){
    case 0: v = w2[k*576 + col]; dh = w2h; dl = w2l; di = u; break;
    case 1: v = (col < 128) ? Wv[k*128 + col] : Wa[k*64 + (col - 128)];
            dh = vabh; dl = vabl; di = u; break;
    case 2: v = Ws[k*64 + col]; dh = wsdh; dl = wsdl; di = u; break;
    case 3: v = Wd[k*64 + col]; dh = wsdh; dl = wsdl; di = 4096 + u; break;
    default:v = Wp[k*64 + col]; dh = wph;  dl = wpl;  di = u; break;
  }
  const unsigned short h = f2bf(v);
  dh[di] = h;
  dl[di] = f2bf(v - bf2f(h));
}

// K1: split-bf16 MFMA node linear: [16 x 64] @ [64 x 128(Ws|Wd)]. 256 thr, 16 rows/block.
__global__ __launch_bounds__(256) void k_node_lin_mfma(
    const float* __restrict__ x, const float* __restrict__ bs,
    const unsigned short* __restrict__ wsdh, const unsigned short* __restrict__ wsdl,
    float* __restrict__ xs, float* __restrict__ xd)
{
  const int tid = threadIdx.x, wid = tid>>6, ln = tid&63;
  const int base = blockIdx.x * 16;
  __shared__ unsigned short hx[2][16][64];
  {
    const int row = tid >> 4, c4 = (tid & 15) * 4;
    const float4 v = *(const float4*)&x[(size_t)(base+row)*64 + c4];
    const int cs = c4 ^ ((row & 7) << 3);
    u16x4 h, l;
    h[0]=f2bf(v.x); h[1]=f2bf(v.y); h[2]=f2bf(v.z); h[3]=f2bf(v.w);
    l[0]=f2bf(v.x-bf2f(h[0])); l[1]=f2bf(v.y-bf2f(h[1]));
    l[2]=f2bf(v.z-bf2f(h[2])); l[3]=f2bf(v.w-bf2f(h[3]));
    *(u16x4*)&hx[0][row][cs] = h;
    *(u16x4*)&hx[1][row][cs] = l;
  }
  __syncthreads();
  const bf16x8 ah0 = ldA(&hx[0][0][0], ln, 0);
  const bf16x8 ah1 = ldA(&hx[0][0][0], ln, 1);
  const bf16x8 al0 = ldA(&hx[1][0][0], ln, 0);
  const bf16x8 al1 = ldA(&hx[1][0][0], ln, 1);
  const bf16x8* Bh = (const bf16x8*)wsdh;
  const bf16x8* Bl = (const bf16x8*)wsdl;
  const int col = wid*16 + (ln & 15);
  const int r0  = (ln >> 4) * 4;
  #pragma unroll
  for (int g = 0; g < 2; g++){
    const int nt = g*4 + wid;
    f32x4 d = {0.f,0.f,0.f,0.f};
    const bf16x8 bh0 = Bh[(nt*2+0)*64 + ln];
    const bf16x8 bl0 = Bl[(nt*2+0)*64 + ln];
    const bf16x8 bh1 = Bh[(nt*2+1)*64 + ln];
    const bf16x8 bl1 = Bl[(nt*2+1)*64 + ln];
    d = __builtin_amdgcn_mfma_f32_16x16x32_bf16(ah0, bh0, d, 0, 0, 0);
    d = __builtin_amdgcn_mfma_f32_16x16x32_bf16(al0, bh0, d, 0, 0, 0);
    d = __builtin_amdgcn_mfma_f32_16x16x32_bf16(ah0, bl0, d, 0, 0, 0);
    d = __builtin_amdgcn_mfma_f32_16x16x32_bf16(ah1, bh1, d, 0, 0, 0);
    d = __builtin_amdgcn_mfma_f32_16x16x32_bf16(al1, bh1, d, 0, 0, 0);
    d = __builtin_amdgcn_mfma_f32_16x16x32_bf16(ah1, bl1, d, 0, 0, 0);
    float* out = (g == 0) ? xs : xd;
    #pragma unroll
    for (int i = 0; i < 4; i++){
      const int row = base + r0 + i;
      float o = d[i];
      if (g == 0 && row % LL == 0) o += bs[col];
      out[(size_t)row*64 + col] = o;
    }
  }
}

// K2: fused edge pass (R16: best verified structure, ~270 us).
__global__ __launch_bounds__(512, 4) void k_edge_fused(
    const float* __restrict__ xsrc, const float* __restrict__ xdst,
    const float* __restrict__ eattr, const float* __restrict__ escal,
    const float* __restrict__ w1, const float* __restrict__ b1,
    const float* __restrict__ lnw, const float* __restrict__ lnb,
    const float* __restrict__ woff,
    const float* __restrict__ U1, const float* __restrict__ V1, const float* __restrict__ Y1,
    const float* __restrict__ U2, const float* __restrict__ V2, const float* __restrict__ Y2,
    const float* __restrict__ ba, const float* __restrict__ adot,
    const float* __restrict__ bv,
    const unsigned short* __restrict__ w2h, const unsigned short* __restrict__ w2l,
    const unsigned short* __restrict__ vabh, const unsigned short* __restrict__ vabl,
    const int* __restrict__ esrc, const int* __restrict__ edst,
    float* __restrict__ accum, float* __restrict__ asum)
{
  const int tid = threadIdx.x;
  const int wid = tid >> 6;     // 0..7
  const int ln  = tid & 63;
  const int base = blockIdx.x * 16;

  __shared__ float sgse[2][16][64];
  __shared__ unsigned short wle[16][576];
  __shared__ unsigned short ms2[9][16][64];
  __shared__ float sU1[9][12], sV1[9][12], sU2[9][12], sV2[9][12];
  __shared__ float syv1[16][12], syv2[16][12];
  float (*se)[64] = sgse[0];
  unsigned short* hpl = (unsigned short*)&sgse[1][0][0];

  for (int i = tid; i < 81; i += 512){
    const int r9 = i/9, c9 = i%9;
    sU1[r9][c9]=U1[i]; sV1[r9][c9]=V1[i]; sU2[r9][c9]=U2[i]; sV2[r9][c9]=V2[i];
  }
  if (tid < 144){
    const int er = tid/9, r = tid%9;
    const float* ea = eattr + (size_t)(base+er)*9;
    float y1 = 0.f, y2 = 0.f;
    #pragma unroll
    for (int l = 0; l < 9; l++){ y1 += ea[l]*Y1[l*9+r]; y2 += ea[l]*Y2[l*9+r]; }
    syv1[er][r] = y1; syv2[er][r] = y2;
  }
  for (int i = tid; i < 1024; i += 512) se[i>>6][i&63] = escal[(size_t)base*64 + i];
  __syncthreads();

  // ---- radial layer 1 + LN + silu -> h hi/lo planes ----
  {
    const int c = ln;
    const float bb = b1[c];
    float hv_[2] = {bb, bb};
    for (int kq = 0; kq < 16; kq++){
      const int k0 = kq*4;
      const float a0 = w1[(k0+0)*64+c], a1 = w1[(k0+1)*64+c], a2 = w1[(k0+2)*64+c], a3 = w1[(k0+3)*64+c];
      #pragma unroll
      for (int j = 0; j < 2; j++){
        const float4 xv = *(const float4*)&se[wid*2+j][k0];
        hv_[j] += xv.x*a0 + xv.y*a1 + xv.z*a2 + xv.w*a3;
      }
    }
    const float lw = lnw[c], lb = lnb[c];
    #pragma unroll
    for (int j = 0; j < 2; j++){
      const float v = hv_[j];
      float s1 = v, s2 = v*v;
      #pragma unroll
      for (int m = 1; m < 64; m <<= 1){ s1 += __shfl_xor(s1, m, 64); s2 += __shfl_xor(s2, m, 64); }
      const float mean = s1 * (1.0f/64.0f);
      const float var  = s2 * (1.0f/64.0f) - mean*mean;
      const float g = (v - mean) * rsqrtf(var + 1e-5f) * lw + lb;
      const float hj = g * sigmoidf_(g);
      const int er = wid*2 + j;
      const int cs = c ^ ((er & 7) << 3);
      const unsigned short hb = f2bf(hj);
      hpl[(0*16 + er)*64 + cs] = hb;
      hpl[(1*16 + er)*64 + cs] = f2bf(hj - bf2f(hb));
    }
  }
  __syncthreads();

  // ---- w2 GEMM via MFMA: [16 x 64] @ [64 x 576] ----
  {
    const bf16x8 ah0 = ldA(hpl, ln, 0);
    const bf16x8 ah1 = ldA(hpl, ln, 1);
    const bf16x8 al0 = ldA(hpl + 16*64, ln, 0);
    const bf16x8 al1 = ldA(hpl + 16*64, ln, 1);
    const bf16x8* Bh = (const bf16x8*)w2h;
    const bf16x8* Bl = (const bf16x8*)w2l;
    const int q = ln >> 4, p = ln & 15;
    #pragma unroll
    for (int t5 = 0; t5 < 5; t5++){
      const int nt = wid + 8*t5;
      if (nt < 36){
        f32x4 d = {0.f,0.f,0.f,0.f};
        const bf16x8 bh0 = Bh[(nt*2+0)*64 + ln];
        const bf16x8 bl0 = Bl[(nt*2+0)*64 + ln];
        const bf16x8 bh1 = Bh[(nt*2+1)*64 + ln];
        const bf16x8 bl1 = Bl[(nt*2+1)*64 + ln];
        d = __builtin_amdgcn_mfma_f32_16x16x32_bf16(ah0, bh0, d, 0, 0, 0);
        d = __builtin_amdgcn_mfma_f32_16x16x32_bf16(al0, bh0, d, 0, 0, 0);
        d = __builtin_amdgcn_mfma_f32_16x16x32_bf16(ah0, bl0, d, 0, 0, 0);
        d = __builtin_amdgcn_mfma_f32_16x16x32_bf16(ah1, bh1, d, 0, 0, 0);
        d = __builtin_amdgcn_mfma_f32_16x16x32_bf16(al1, bh1, d, 0, 0, 0);
        d = __builtin_amdgcn_mfma_f32_16x16x32_bf16(ah1, bl1, d, 0, 0, 0);
        const int col = nt*16 + p;
        const float wo = woff[col];
        #pragma unroll
        for (int i = 0; i < 4; i++) wle[q*4+i][col] = f2bf(d[i] + wo);
      }
    }
  }
  __syncthreads();

  // ---- gather + cp_tp1 -> msg2 bf16 ----
  {
    const int c = ln;
    const int er0 = wid*2;
    float msg[2][9];
    #pragma unroll
    for (int j = 0; j < 2; j++){
      const int e  = base + er0 + j;
      const int src = esrc[e], dst = edst[e];
      const float* ps = xsrc + (size_t)src*576 + c;
      const float* pd = xdst + (size_t)dst*576 + c;
      #pragma unroll
      for (int l = 0; l < 9; l++) msg[j][l] = ps[l*64] + pd[l*64];
    }
    float xv[2][9];
    #pragma unroll
    for (int j = 0; j < 2; j++)
      #pragma unroll
      for (int r = 0; r < 9; r++) xv[j][r] = 0.f;
    #pragma unroll
    for (int l = 0; l < 9; l++){
      const float4 v0 = *(const float4*)&sV1[l][0];
      const float4 v1 = *(const float4*)&sV1[l][4];
      const float  v2 = sV1[l][8];
      #pragma unroll
      for (int j = 0; j < 2; j++){
        const float m = msg[j][l];
        xv[j][0] += m*v0.x; xv[j][1] += m*v0.y; xv[j][2] += m*v0.z; xv[j][3] += m*v0.w;
        xv[j][4] += m*v1.x; xv[j][5] += m*v1.y; xv[j][6] += m*v1.z; xv[j][7] += m*v1.w;
        xv[j][8] += m*v2;
      }
    }
    #pragma unroll
    for (int j = 0; j < 2; j++){
      const int er = er0 + j;
      const float4 s0 = *(const float4*)&syv1[er][0];
      const float4 s1 = *(const float4*)&syv1[er][4];
      const float  s2 = syv1[er][8];
      const float sy[9] = {s0.x,s0.y,s0.z,s0.w,s1.x,s1.y,s1.z,s1.w,s2};
      #pragma unroll
      for (int r = 0; r < 9; r++) xv[j][r] *= sy[r] * bf2f(wle[er][r*64+c]);
    }
    #pragma unroll
    for (int l = 0; l < 9; l++){
      const float4 u0 = *(const float4*)&sU1[l][0];
      const float4 u1 = *(const float4*)&sU1[l][4];
      const float  u2 = sU1[l][8];
      #pragma unroll
      for (int j = 0; j < 2; j++){
        const int er = er0 + j;
        const float m2 = xv[j][0]*u0.x + xv[j][1]*u0.y + xv[j][2]*u0.z + xv[j][3]*u0.w
                       + xv[j][4]*u1.x + xv[j][5]*u1.y + xv[j][6]*u1.z + xv[j][7]*u1.w
                       + xv[j][8]*u2;
        ms2[l][er][c ^ ((er & 7) << 3)] = f2bf(m2);
      }
    }
  }
  __syncthreads();

  // ---- value GEMM (waves 0..3, regs) / gate+alpha (waves 4..7 -> sgse) ----
  f32x4 vacc[9];
  {
    const bf16x8* Bh = (const bf16x8*)vabh;
    const bf16x8* Bl = (const bf16x8*)vabl;
    if (wid < 4){
      const int nt = wid;
      const bf16x8 bh0 = Bh[(nt*2+0)*64 + ln];
      const bf16x8 bl0 = Bl[(nt*2+0)*64 + ln];
      const bf16x8 bh1 = Bh[(nt*2+1)*64 + ln];
      const bf16x8 bl1 = Bl[(nt*2+1)*64 + ln];
      #pragma unroll
      for (int l = 0; l < 9; l++){
        const bf16x8 a0 = ldA(&ms2[l][0][0], ln, 0);
        const bf16x8 a1 = ldA(&ms2[l][0][0], ln, 1);
        f32x4 d = {0.f,0.f,0.f,0.f};
        d = __builtin_amdgcn_mfma_f32_16x16x32_bf16(a0, bh0, d, 0, 0, 0);
        d = __builtin_amdgcn_mfma_f32_16x16x32_bf16(a0, bl0, d, 0, 0, 0);
        d = __builtin_amdgcn_mfma_f32_16x16x32_bf16(a1, bh1, d, 0, 0, 0);
        d = __builtin_amdgcn_mfma_f32_16x16x32_bf16(a1, bl1, d, 0, 0, 0);
        vacc[l] = d;
      }
    } else {
      const int w4 = wid - 4;
      const bf16x8 a0 = ldA(&ms2[0][0][0], ln, 0);
      const bf16x8 a1 = ldA(&ms2[0][0][0], ln, 1);
      const int q = ln >> 4, p = ln & 15;
      #pragma unroll
      for (int gg = 0; gg < 2; gg++){
        const int nt = 4 + gg*4 + w4;
        const bf16x8 bh0 = Bh[(nt*2+0)*64 + ln];
        const bf16x8 bl0 = Bl[(nt*2+0)*64 + ln];
        const bf16x8 bh1 = Bh[(nt*2+1)*64 + ln];
        const bf16x8 bl1 = Bl[(nt*2+1)*64 + ln];
        f32x4 d = {0.f,0.f,0.f,0.f};
        d = __builtin_amdgcn_mfma_f32_16x16x32_bf16(a0, bh0, d, 0, 0, 0);
        d = __builtin_amdgcn_mfma_f32_16x16x32_bf16(a0, bl0, d, 0, 0, 0);
        d = __builtin_amdgcn_mfma_f32_16x16x32_bf16(a1, bh1, d, 0, 0, 0);
        d = __builtin_amdgcn_mfma_f32_16x16x32_bf16(a1, bl1, d, 0, 0, 0);
        #pragma unroll
        for (int i = 0; i < 4; i++) sgse[gg][q*4+i][w4*16+p] = d[i];
      }
    }
  }
  __syncthreads();

  // ---- waves 0..3: bounce value-D into ms2 (bf16, XOR-swizzled rows) ----
  if (wid < 4){
    const int col = wid*16 + (ln & 15);
    const int r0  = (ln >> 4) * 4;
    #pragma unroll
    for (int l = 0; l < 9; l++)
      #pragma unroll
      for (int i = 0; i < 4; i++){
        const int er = r0 + i;
        ms2[l][er][col ^ ((er & 7) << 3)] = f2bf(vacc[l][i]);
      }
  }
  __syncthreads();

  // ---- epilogue: ALL 8 waves, 2 edges/wave, lane = col ----
  {
    const int c = ln;
    const int er0 = wid*2;
    const float bvc = bv[c], bgc = bv[64+c], bac = ba[c], adc = adot[c];
    int dsti[2]; float gsv[2], pev[2];
    #pragma unroll
    for (int j = 0; j < 2; j++){
      const int er = er0 + j;
      dsti[j] = edst[base + er];
      gsv[j] = sigmoidf_(sgse[0][er][c] + bgc);
      const float a  = sgse[1][er][c] + bac;
      const float sl = 0.2f*a + 0.8f*a*sigmoidf_(a);
      float t = sl * adc;
      t += __shfl_xor(t, 1, 64);
      t += __shfl_xor(t, 2, 64);
      t += __shfl_xor(t, 4, 64);
      pev[j] = __expf(t);     // unnormalized softmax weight (max-shift cancels)
      if ((c & 7) == 0) atomicAdd(&asum[(size_t)dsti[j]*8 + (c>>3)], pev[j]);
    }
    float tmp2[2][9];
    #pragma unroll
    for (int j = 0; j < 2; j++)
      #pragma unroll
      for (int r = 0; r < 9; r++) tmp2[j][r] = 0.f;
    #pragma unroll
    for (int l = 0; l < 9; l++){
      const float4 v0 = *(const float4*)&sV2[l][0];
      const float4 v1 = *(const float4*)&sV2[l][4];
      const float  v2 = sV2[l][8];
      #pragma unroll
      for (int j = 0; j < 2; j++){
        const int er = er0 + j;
        float v = bf2f(ms2[l][er][c ^ ((er & 7) << 3)]);
        if (l == 0){ v += bvc; v = v * sigmoidf_(v); }
        else v *= gsv[j];
        tmp2[j][0] += v*v0.x; tmp2[j][1] += v*v0.y; tmp2[j][2] += v*v0.z; tmp2[j][3] += v*v0.w;
        tmp2[j][4] += v*v1.x; tmp2[j][5] += v*v1.y; tmp2[j][6] += v*v1.z; tmp2[j][7] += v*v1.w;
        tmp2[j][8] += v*v2;
      }
    }
    #pragma unroll
    for (int j = 0; j < 2; j++){
      const int er = er0 + j;
      const float4 s0 = *(const float4*)&syv2[er][0];
      const float4 s1 = *(const float4*)&syv2[er][4];
      const float  s2 = syv2[er][8];
      const float sy[9] = {s0.x,s0.y,s0.z,s0.w,s1.x,s1.y,s1.z,s1.w,s2};
      #pragma unroll
      for (int r = 0; r < 9; r++) tmp2[j][r] *= sy[r] * bf2f(wle[er][r*64+c]) * pev[j];
    }
    #pragma unroll
    for (int l = 0; l < 9; l++){
      const float4 u0 = *(const float4*)&sU2[l][0];
      const float4 u1 = *(const float4*)&sU2[l][4];
      const float  u2 = sU2[l][8];
      #pragma unroll
      for (int j = 0; j < 2; j++){
        const float o = tmp2[j][0]*u0.x + tmp2[j][1]*u0.y + tmp2[j][2]*u0.z + tmp2[j][3]*u0.w
                      + tmp2[j][4]*u1.x + tmp2[j][5]*u1.y + tmp2[j][6]*u1.z + tmp2[j][7]*u1.w
                      + tmp2[j][8]*u2;
        atomicAdd(accum + (size_t)dsti[j]*576 + l*64 + c, o);
      }
    }
  }
}

// K3: normalize + proj via split-bf16 MFMA. 256 thr, 16 rows/block.
__global__ __launch_bounds__(256) void k_norm_proj_mfma(
    const float* __restrict__ acc, const float* __restrict__ asum,
    const unsigned short* __restrict__ wph, const unsigned short* __restrict__ wpl,
    const float* __restrict__ bp, float* __restrict__ out)
{
  const int tid = threadIdx.x, wid = tid>>6, ln = tid&63;
  const int base = blockIdx.x * 16;
  __shared__ unsigned short hx[2][16][64];
  {
    const int row = tid >> 4, c4 = (tid & 15) * 4;
    const int grow = base + row;
    const float s = 1.0f / (asum[(size_t)(grow/9)*8 + (c4>>3)] + 1e-16f);
    float4 v = *(const float4*)&acc[(size_t)grow*64 + c4];
    v.x *= s; v.y *= s; v.z *= s; v.w *= s;
    const int cs = c4 ^ ((row & 7) << 3);
    u16x4 h, l;
    h[0]=f2bf(v.x); h[1]=f2bf(v.y); h[2]=f2bf(v.z); h[3]=f2bf(v.w);
    l[0]=f2bf(v.x-bf2f(h[0])); l[1]=f2bf(v.y-bf2f(h[1]));
    l[2]=f2bf(v.z-bf2f(h[2])); l[3]=f2bf(v.w-bf2f(h[3]));
    *(u16x4*)&hx[0][row][cs] = h;
    *(u16x4*)&hx[1][row][cs] = l;
  }
  __syncthreads();
  const bf16x8 ah0 = ldA(&hx[0][0][0], ln, 0);
  const bf16x8 ah1 = ldA(&hx[0][0][0], ln, 1);
  const bf16x8 al0 = ldA(&hx[1][0][0], ln, 0);
  const bf16x8 al1 = ldA(&hx[1][0][0], ln, 1);
  const bf16x8* Bh = (const bf16x8*)wph;
  const bf16x8* Bl = (const bf16x8*)wpl;
  const int nt = wid;
  f32x4 d = {0.f,0.f,0.f,0.f};
  const bf16x8 bh0 = Bh[(nt*2+0)*64 + ln];
  const bf16x8 bl0 = Bl[(nt*2+0)*64 + ln];
  const bf16x8 bh1 = Bh[(nt*2+1)*64 + ln];
  const bf16x8 bl1 = Bl[(nt*2+1)*64 + ln];
  d = __builtin_amdgcn_mfma_f32_16x16x32_bf16(ah0, bh0, d, 0, 0, 0);
  d = __builtin_amdgcn_mfma_f32_16x16x32_bf16(al0, bh0, d, 0, 0, 0);
  d = __builtin_amdgcn_mfma_f32_16x16x32_bf16(ah0, bl0, d, 0, 0, 0);
  d = __builtin_amdgcn_mfma_f32_16x16x32_bf16(ah1, bh1, d, 0, 0, 0);
  d = __builtin_amdgcn_mfma_f32_16x16x32_bf16(al1, bh1, d, 0, 0, 0);
  d = __builtin_amdgcn_mfma_f32_16x16x32_bf16(ah1, bl1, d, 0, 0, 0);
  const int col = wid*16 + (ln & 15);
  const int r0  = (ln >> 4) * 4;
  #pragma unroll
  for (int i = 0; i < 4; i++){
    const int row = base + r0 + i;
    float o = d[i];
    if (row % LL == 0) o += bp[col];
    out[(size_t)row*64 + col] = o;
  }
}

extern "C" void kernel_launch(void* const* d_in, const int* in_sizes, int n_in,
                              void* d_out, int out_size, void* d_ws, size_t ws_size,
                              hipStream_t stream)
{
  (void)in_sizes; (void)n_in; (void)out_size;
  const float* node_input = (const float*)d_in[0];
  const float* edge_attr  = (const float*)d_in[1];
  const float* edge_scal  = (const float*)d_in[2];
  const float* W_src   = (const float*)d_in[3];
  const float* b_src   = (const float*)d_in[4];
  const float* W_dst   = (const float*)d_in[5];
  const float* rad_w1  = (const float*)d_in[6];
  const float* rad_b1  = (const float*)d_in[7];
  const float* rad_ln_w= (const float*)d_in[8];
  const float* rad_ln_b= (const float*)d_in[9];
  const float* rad_w2  = (const float*)d_in[10];
  const float* rad_off = (const float*)d_in[11];
  const float* U1 = (const float*)d_in[12];
  const float* V1 = (const float*)d_in[13];
  const float* Y1 = (const float*)d_in[14];
  const float* U2 = (const float*)d_in[15];
  const float* V2 = (const float*)d_in[16];
  const float* Y2 = (const float*)d_in[17];
  const float* W_alpha = (const float*)d_in[18];
  const float* b_alpha = (const float*)d_in[19];
  const float* alpha_dot = (const float*)d_in[20];
  const float* W_value = (const float*)d_in[21];
  const float* b_value = (const float*)d_in[22];
  const float* W_proj  = (const float*)d_in[23];
  const float* b_proj  = (const float*)d_in[24];
  const int* esrc = (const int*)d_in[25];
  const int* edst = (const int*)d_in[26];

  float* xsrc  = (float*)d_ws;
  float* xdst  = xsrc + NLC;
  float* accum = xdst + NLC;
  float* asum  = accum + NLC;
  unsigned short* w2h  = (unsigned short*)(asum + (size_t)NN*HH);
  unsigned short* w2l  = w2h + 36*1024;
  unsigned short* vabh = w2l + 36*1024;
  unsigned short* vabl = vabh + 12*1024;
  unsigned short* wsdh = vabl + 12*1024;
  unsigned short* wsdl = wsdh + 8*1024;
  unsigned short* wph  = wsdl + 8*1024;
  unsigned short* wpl  = wph  + 4*1024;
  const size_t need = ((size_t)3*NLC + (size_t)NN*HH)*sizeof(float)
                    + (size_t)(2*36*1024 + 2*12*1024 + 2*8*1024 + 2*4*1024)*sizeof(unsigned short);
  if (ws_size < need) return;

  hipMemsetAsync(accum, 0, (size_t)NLC*sizeof(float), stream);
  hipMemsetAsync(asum, 0, (size_t)NN*HH*sizeof(float), stream);

  k_prep_all<<<240, 256, 0, stream>>>(rad_w2, W_value, W_alpha, W_src, W_dst, W_proj,
      w2h, w2l, vabh, vabl, wsdh, wsdl, wph, wpl);
  k_node_lin_mfma<<<NN*LL/16, 256, 0, stream>>>(node_input, b_src, wsdh, wsdl, xsrc, xdst);
  k_edge_fused<<<EE/16, 512, 0, stream>>>(xsrc, xdst, edge_attr, edge_scal,
      rad_w1, rad_b1, rad_ln_w, rad_ln_b, rad_off,
      U1, V1, Y1, U2, V2, Y2,
      b_alpha, alpha_dot, b_value,
      w2h, w2l, vabh, vabl, esrc, edst, accum, asum);
  k_norm_proj_mfma<<<NN*LL/16, 256, 0, stream>>>(accum, asum, wph, wpl, b_proj, (float*)d_out);
}